// Round 5
// baseline (709.625 us; speedup 1.0000x reference)
//
#include <hip/hip_runtime.h>
#include <cstdint>
#include <cstddef>

#define S_   2048
#define H_   16
#define KVH_ 2
#define D_   256

typedef __attribute__((ext_vector_type(4))) float          float4v;
typedef __attribute__((ext_vector_type(4))) float          floatx4;
typedef __attribute__((ext_vector_type(8))) unsigned short ushort8v;
typedef __attribute__((ext_vector_type(4))) unsigned short ushort4v;
typedef __attribute__((ext_vector_type(8))) short          short8;

__device__ __forceinline__ float bf2f(unsigned short u){
  union{float f; unsigned int i;} v; v.i = ((unsigned int)u)<<16; return v.f;
}
__device__ __forceinline__ unsigned short f2bf(float f){
  union{float f; unsigned int i;} v; v.f = f;
  unsigned int r = v.i + 0x7FFFu + ((v.i>>16)&1u);   // RNE
  return (unsigned short)(r>>16);
}
__device__ __forceinline__ void gld16(const void* g, void* l){
  __builtin_amdgcn_global_load_lds(
      (const __attribute__((address_space(1))) unsigned int*)g,
      (__attribute__((address_space(3))) unsigned int*)l, 16, 0, 0);
}

// ---------------------------------------------------------------------------
// Plain fp32 -> bf16 convert (hs). 8 elems/thread.
// ---------------------------------------------------------------------------
__global__ __launch_bounds__(256) void conv_k(
    const float* __restrict__ in, unsigned short* __restrict__ out)
{
  const size_t i = ((size_t)blockIdx.x*256 + threadIdx.x)*8;
  float4v a0 = *(const float4v*)(in + i), a1 = *(const float4v*)(in + i + 4);
  ushort8v u;
#pragma unroll
  for (int e=0;e<4;e++){ u[e]=f2bf(a0[e]); u[e+4]=f2bf(a1[e]); }
  *(ushort8v*)(out + i) = u;
}

// ---------------------------------------------------------------------------
// Transpose-convert: in fp32 [K][N] -> out bf16 [N][K]. 64x64 LDS tiles.
// ---------------------------------------------------------------------------
__global__ __launch_bounds__(256) void tconv_k(
    const float* __restrict__ in, unsigned short* __restrict__ out, int K, int N)
{
  __shared__ unsigned short T[64][72];
  const int n0 = blockIdx.x<<6, k0 = blockIdx.y<<6;
  const int t = threadIdx.x, r = t>>2, c = (t&3)<<4;
  const float* ip = in + (size_t)(k0+r)*N + n0 + c;
  float4v a0=*(const float4v*)ip,     a1=*(const float4v*)(ip+4);
  float4v a2=*(const float4v*)(ip+8), a3=*(const float4v*)(ip+12);
  ushort8v u0,u1;
#pragma unroll
  for (int e=0;e<4;e++){ u0[e]=f2bf(a0[e]); u0[e+4]=f2bf(a1[e]);
                         u1[e]=f2bf(a2[e]); u1[e+4]=f2bf(a3[e]); }
  *(ushort8v*)&T[r][c] = u0; *(ushort8v*)&T[r][c+8] = u1;
  __syncthreads();
  ushort8v o0,o1;
#pragma unroll
  for (int j=0;j<8;j++){ o0[j]=T[c+j][r]; o1[j]=T[c+8+j][r]; }
  unsigned short* op = out + (size_t)(n0+r)*K + k0 + c;
  *(ushort8v*)op = o0; *(ushort8v*)(op+8) = o1;
}

// ---------------------------------------------------------------------------
// GEMM: C(MxN) = A(MxK) @ Bt(NxK)^T, bf16 MFMA, fp32 acc.
// BM=BN=128, BK=32; double-buffered LDS, ONE barrier per k-iter:
//   barrier -> prefetch tile it+1 (gld16, buf^1) -> compute tile it (buf).
// The barrier's vmcnt drain only hits loads issued one full compute phase
// ago -> staging latency hidden (flash R4 pattern).
// Grid is M-major (gm = blockIdx.x): consecutive blocks share one B panel.
// MODE 0: scatter q(B,H,S,D)/gate(B,S,H,D)/k(B,KVH,S,D)/v^T(B,KVH,S/32,D,32)
// MODE 3: out fp32 row-major [M][N]
// ---------------------------------------------------------------------------
template<int MODE>
__global__ __launch_bounds__(256,2) void gemm_k(
    const unsigned short* __restrict__ A, const unsigned short* __restrict__ Bt,
    void* __restrict__ out0, void* __restrict__ out1, int K, int N)
{
  __shared__ unsigned short Ash[2][128*32];
  __shared__ unsigned short Bsh[2][128*32];
  const int tid  = threadIdx.x;
  const int gm   = blockIdx.x<<7, gn = blockIdx.y<<7;
  const int lane = tid & 63, wave = tid >> 6;
  const int quad = lane >> 4, col = lane & 15;
  const int wm   = (wave>>1)<<6, wn = (wave&1)<<6;
  const int rowoff = lane>>2;
  const int chunk  = (lane&3) ^ (rowoff&3);
  const int ra0 = wave<<4, ra1 = 64 + (wave<<4);
  const unsigned short* Ab = A  + (size_t)gm*K;
  const unsigned short* Bb = Bt + (size_t)gn*K;
  const int cf = (quad ^ (col&3))<<3;

  floatx4 acc[4][4];
#pragma unroll
  for (int i=0;i<4;i++)
#pragma unroll
    for (int j=0;j<4;j++) acc[i][j] = (floatx4)0.f;

  const int niter = K>>5;
  {           // prologue: stage tile 0 into buf 0
    const int ko = chunk*8;
    gld16(Ab + (size_t)(ra0+rowoff)*K + ko, &Ash[0][ra0*32]);
    gld16(Ab + (size_t)(ra1+rowoff)*K + ko, &Ash[0][ra1*32]);
    gld16(Bb + (size_t)(ra0+rowoff)*K + ko, &Bsh[0][ra0*32]);
    gld16(Bb + (size_t)(ra1+rowoff)*K + ko, &Bsh[0][ra1*32]);
  }
  for (int it=0; it<niter; ++it){
    const int buf = it&1;
    __syncthreads();                     // drains tile-it staging
    if (it+1 < niter){                   // prefetch tile it+1 into buf^1
      const int ko = (it+1)*32 + chunk*8;
      gld16(Ab + (size_t)(ra0+rowoff)*K + ko, &Ash[buf^1][ra0*32]);
      gld16(Ab + (size_t)(ra1+rowoff)*K + ko, &Ash[buf^1][ra1*32]);
      gld16(Bb + (size_t)(ra0+rowoff)*K + ko, &Bsh[buf^1][ra0*32]);
      gld16(Bb + (size_t)(ra1+rowoff)*K + ko, &Bsh[buf^1][ra1*32]);
    }
    short8 af[4], bfr[4];
#pragma unroll
    for (int mi=0;mi<4;mi++) af[mi]  = *(const short8*)&Ash[buf][(wm+mi*16+col)*32 + cf];
#pragma unroll
    for (int ni=0;ni<4;ni++) bfr[ni] = *(const short8*)&Bsh[buf][(wn+ni*16+col)*32 + cf];
#pragma unroll
    for (int mi=0;mi<4;mi++)
#pragma unroll
      for (int ni=0;ni<4;ni++)
        acc[mi][ni] = __builtin_amdgcn_mfma_f32_16x16x32_bf16(af[mi], bfr[ni], acc[mi][ni], 0,0,0);
  }

#pragma unroll
  for (int mi=0;mi<4;mi++){
#pragma unroll
    for (int r=0;r<4;r++){
      const int m = gm + wm + mi*16 + quad*4 + r;
      const int b = m >> 11, s = m & 2047;
#pragma unroll
      for (int ni=0;ni<4;ni++){
        const int n = gn + wn + ni*16 + col;
        const float v = acc[mi][ni][r];
        if (MODE==0){
          if (n < 8192){
            const int h = n >> 9, dd = n & 511;
            if (dd < 256)   // q -> (B,H,S,D)
              ((unsigned short*)out0)[(((size_t)b*H_ + h)*S_ + s)*D_ + dd] = f2bf(v);
            else            // gate -> (B,S,H,D)
              ((unsigned short*)out1)[((size_t)m*H_ + h)*D_ + (dd-256)] = f2bf(v);
          } else {
            const int n2 = n - 8192;
            if (n2 < 512){  // k -> (B,KVH,S,D)
              const int kvh = n2 >> 8, dd = n2 & 255;
              ((unsigned short*)out0)[(size_t)(67108864/2) + (((size_t)b*KVH_ + kvh)*S_ + s)*D_ + dd] = f2bf(v);
            } else {        // v^T chunk-tiled (B,KVH,S/32,D,32)
              const int nv2 = n2 - 512;
              const int kvh = nv2 >> 8, dd = nv2 & 255;
              ((unsigned short*)out0)[(size_t)(71303168/2) + ((((size_t)b*KVH_ + kvh)*64 + (s>>5))*256 + dd)*32 + (s&31)] = f2bf(v);
            }
          }
        } else {
          ((float*)out0)[(size_t)m*N + n] = v;
        }
      }
    }
  }
}

// ---------------------------------------------------------------------------
// RMSNorm(D=256) + RoPE(first 64 dims), in-place on bf16 rows. 1 wave / row.
// ---------------------------------------------------------------------------
__global__ __launch_bounds__(256,2) void normrope_k(
    unsigned short* __restrict__ x, const float* __restrict__ w,
    const float* __restrict__ cosp, const float* __restrict__ sinp, int heads)
{
  const int lane = threadIdx.x & 63;
  const int row  = blockIdx.x*4 + (threadIdx.x>>6);
  const int s    = row & (S_-1);
  const int b    = (row / S_) / heads;
  unsigned short* xp = x + (size_t)row * D_;
  const int d = lane*4;
  ushort4v xv = *(const ushort4v*)(xp + d);
  float v0=bf2f(xv[0]), v1=bf2f(xv[1]), v2=bf2f(xv[2]), v3=bf2f(xv[3]);
  float ss = v0*v0+v1*v1+v2*v2+v3*v3;
#pragma unroll
  for (int off=1; off<64; off<<=1) ss += __shfl_xor(ss, off, 64);
  const float rstd = rsqrtf(ss*(1.f/256.f) + 1e-6f);
  float nv[4] = { v0*rstd*(1.f+w[d]),   v1*rstd*(1.f+w[d+1]),
                  v2*rstd*(1.f+w[d+2]), v3*rstd*(1.f+w[d+3]) };
  float ov[4];
#pragma unroll
  for (int j=0;j<4;j++){
    const float other = __shfl_xor(nv[j], 8, 64);
    float o = nv[j];
    if (lane < 16){
      const float c  = cosp[((size_t)b*S_+s)*64 + d + j];
      const float sn = sinp[((size_t)b*S_+s)*64 + d + j];
      o = (lane < 8) ? (nv[j]*c - other*sn) : (nv[j]*c + other*sn);
    }
    ov[j] = o;
  }
  ushort4v ou;
#pragma unroll
  for (int j=0;j<4;j++) ou[j] = f2bf(ov[j]);
  *(ushort4v*)(xp + d) = ou;
}

// ---------------------------------------------------------------------------
// Flash attention, causal, GQA, sigmoid-gate. Balanced strip-pair version:
// 256 blocks, block = (b, h, pair p): processes q-strips qt=p and qt=15-p
// sequentially -> every block runs exactly 68 chunk-iterations (no tail).
// Per strip: kv chunks of 32, K/V double-buffered LDS via global_load_lds,
// prefetch-across-barrier (one barrier/chunk); unpadded XOR-swizzled LDS;
// no-max softmax; coalesced LDS-repacked epilogue fused with sigmoid(gate).
// ---------------------------------------------------------------------------
__global__ __launch_bounds__(256,2) void flash_k(
    const unsigned short* __restrict__ qb, const unsigned short* __restrict__ kbp,
    const unsigned short* __restrict__ vtp, const unsigned short* __restrict__ gb,
    unsigned short* __restrict__ ob)
{
  // SH layout (ushorts): K[2][8192] | V[2][8192] | P[4][2][640]  = 75776 B
  __shared__ unsigned short SH[2*8192 + 2*8192 + 4*2*640];
  unsigned short* Kb0 = SH;
  unsigned short* Vb0 = SH + 16384;
  const int gid = blockIdx.x;
  const int p   = gid & 7;
  const int h   = (gid>>3) & 15;
  const int b   = gid >> 7;
  const int kvh = h >> 3;
  const int tid = threadIdx.x, wave = tid>>6, lane = tid&63;
  const int quad = lane>>4, col = lane&15;
  unsigned short* Psh = SH + 32768 + wave*1280;   // [2][640], stride 40

  // per-thread staging offsets (within one 8192-elem chunk)
  int kOff[4], vOff[4];
#pragma unroll
  for (int j=0;j<4;j++){
    const int krow = wave*8 + j*2 + (lane>>5);
    kOff[j] = krow*256 + ((lane&31) ^ (krow&7))*8;
    const int vrow = wave*64 + j*16 + (lane>>2);
    vOff[j] = vrow*32 + ((lane&3) ^ (vrow&3))*8;
  }
  const unsigned short* Kg = kbp + ((size_t)b*KVH_ + kvh)*S_*D_;
  const unsigned short* Vg = vtp + ((size_t)b*KVH_ + kvh)*S_*D_;

  for (int sp=0; sp<2; ++sp){
    const int qt = sp ? (15-p) : p;
    const int qw = qt*128 + wave*32;
    const int nch = 4*qt + 4;

    // Q fragments (A[m=col][k=quad*8+j])
    short8 qf[2][8];
#pragma unroll
    for (int m=0;m<2;m++){
      const unsigned short* qr = qb + (((size_t)b*H_ + h)*S_ + (qw + m*16 + col))*D_;
#pragma unroll
      for (int dc=0; dc<8; ++dc) qf[m][dc] = *(const short8*)(qr + dc*32 + quad*8);
    }
    floatx4 O[2][16];
#pragma unroll
    for (int m=0;m<2;m++)
#pragma unroll
      for (int i=0;i<16;i++) O[m][i] = (floatx4)0.f;
    float lacc[2][4] = {{0.f,0.f,0.f,0.f},{0.f,0.f,0.f,0.f}};

    __syncthreads();   // protect LDS from prior strip's epilogue readers
    // prologue: stage chunk 0 into buf 0
#pragma unroll
    for (int j=0;j<4;j++){
      gld16(Kg + kOff[j], Kb0 + wave*2048 + j*512);
      gld16(Vg + vOff[j], Vb0 + wave*2048 + j*512);
    }

    int buf = 0;
    for (int kc=0; kc<nch; ++kc){
      __syncthreads();                       // drains chunk-kc staging
      if (kc+1 < nch){                       // prefetch kc+1 into buf^1
        const unsigned short* kg = Kg + (size_t)(kc+1)*8192;
        const unsigned short* vg = Vg + (size_t)(kc+1)*8192;
        unsigned short* kl = Kb0 + (buf^1)*8192 + wave*2048;
        unsigned short* vl = Vb0 + (buf^1)*8192 + wave*2048;
#pragma unroll
        for (int j=0;j<4;j++){
          gld16(kg + kOff[j], kl + j*512);
          gld16(vg + vOff[j], vl + j*512);
        }
      }
      const unsigned short* Ksh = Kb0 + buf*8192;
      const unsigned short* Vt  = Vb0 + buf*8192;

      // ---- QK^T (2 m-tiles x 2 n-tiles over D=256)
      floatx4 sc[2][2];
#pragma unroll
      for (int m=0;m<2;m++){ sc[m][0]=(floatx4)0.f; sc[m][1]=(floatx4)0.f; }
#pragma unroll
      for (int dc=0; dc<8; ++dc){
#pragma unroll
        for (int nt=0;nt<2;nt++){
          const int row = nt*16+col;
          short8 kf = *(const short8*)&Ksh[row*256 + (((dc*4+quad) ^ (row&7))<<3)];
          sc[0][nt] = __builtin_amdgcn_mfma_f32_16x16x32_bf16(qf[0][dc], kf, sc[0][nt], 0,0,0);
          sc[1][nt] = __builtin_amdgcn_mfma_f32_16x16x32_bf16(qf[1][dc], kf, sc[1][nt], 0,0,0);
        }
      }
      // ---- mask+exp -> Psh (per-wave, no barrier) -> pf
      short8 pf[2];
#pragma unroll
      for (int m=0;m<2;m++){
#pragma unroll
        for (int r=0;r<4;r++){
          const int q = qw + m*16 + quad*4 + r;
          float psum = 0.f;
#pragma unroll
          for (int nt=0;nt<2;nt++){
            const int kv = kc*32 + nt*16 + col;
            const float pv = (kv<=q) ? __expf(sc[m][nt][r]*0.0625f) : 0.f;
            psum += pv;
            Psh[m*640 + (quad*4+r)*40 + nt*16 + col] = f2bf(pv);
          }
          lacc[m][r] += psum;
        }
        pf[m] = *(const short8*)&Psh[m*640 + col*40 + quad*8];
      }
      // ---- PV: V frags read once, used for both m
#pragma unroll
      for (int nc=0;nc<16;nc++){
        const int row = nc*16+col;
        short8 vf = *(const short8*)&Vt[row*32 + ((quad ^ (row&3))<<3)];
        O[0][nc] = __builtin_amdgcn_mfma_f32_16x16x32_bf16(pf[0], vf, O[0][nc], 0,0,0);
        O[1][nc] = __builtin_amdgcn_mfma_f32_16x16x32_bf16(pf[1], vf, O[1][nc], 0,0,0);
      }
      buf ^= 1;
    }

    // ---- epilogue: repack O via LDS, coalesced gate/store
    __syncthreads();                         // K/V buffers now free
    unsigned short* rep = SH + wave*8192;    // 32q x 256d per wave
#pragma unroll
    for (int m=0;m<2;m++){
#pragma unroll
      for (int r=0;r<4;r++){
        float s = lacc[m][r];
        s += __shfl_xor(s,1,64); s += __shfl_xor(s,2,64);
        s += __shfl_xor(s,4,64); s += __shfl_xor(s,8,64);
        const float inv = 1.f/s;
        const int rrow = (m*16 + quad*4 + r)*256;
#pragma unroll
        for (int nc=0;nc<16;nc++)
          rep[rrow + nc*16 + col] = f2bf(O[m][nc][r]*inv);
      }
    }
    // each j: 64 lanes cover 1KB contiguous (2 q-rows)
#pragma unroll
    for (int j=0;j<16;j++){
      const int e  = j*512 + lane*8;
      const int ql = j*2 + (lane>>5);
      const int d  = (lane&31)*8;
      ushort8v ov = *(const ushort8v*)&rep[e];
      const size_t base = (((size_t)b*S_ + (qt*128 + wave*32 + ql))*H_ + h)*D_ + d;
      ushort8v gv = *(const ushort8v*)(gb + base);
      ushort8v wv;
#pragma unroll
      for (int k=0;k<8;k++){
        const float gvf = bf2f(gv[k]);
        const float sg  = 1.f/(1.f + __expf(-gvf));
        wv[k] = f2bf(bf2f(ov[k])*sg);
      }
      *(ushort8v*)(ob + base) = wv;
    }
  }
}

// ---------------------------------------------------------------------------
extern "C" void kernel_launch(void* const* d_in, const int* in_sizes, int n_in,
                              void* d_out, int out_size, void* d_ws, size_t ws_size,
                              hipStream_t stream)
{
  const float* hs   = (const float*)d_in[0];
  const float* cosp = (const float*)d_in[1];
  const float* sinp = (const float*)d_in[2];
  const float* Wq   = (const float*)d_in[3];
  const float* Wk   = (const float*)d_in[4];
  const float* Wv   = (const float*)d_in[5];
  const float* Wo   = (const float*)d_in[6];
  const float* qw   = (const float*)d_in[7];
  const float* kw   = (const float*)d_in[8];
  float* out = (float*)d_out;

  char* w = (char*)d_ws;                       // 124 MB total
  unsigned short* q_bf  = (unsigned short*)(w);               // 33.5MB (B,H,S,D)
  unsigned short* gate  = (unsigned short*)(w + 33554432);    // 33.5MB (B,S,H,D)
  unsigned short* k_bf  = (unsigned short*)(w + 67108864);    //  4.2MB (B,KVH,S,D)
  unsigned short* v_t   = (unsigned short*)(w + 71303168);    //  4.2MB (B,KVH,S/32,D,32)
  unsigned short* hs_bf = (unsigned short*)(w + 75497472);    // 16.8MB [4096][2048]
  unsigned short* wq_t  = (unsigned short*)(w + 92274688);    // 33.5MB [8192][2048]
  unsigned short* wkv_t = (unsigned short*)(w + 125829120);   //  4.2MB [1024][2048]
  unsigned short* wo_t  = (unsigned short*)(w + 92274688);    // 16.8MB overlay after gemm0
  unsigned short* attn  = gate;                               // in-place overlay

  // 0) convert/transpose operands to bf16
  conv_k<<<4096, 256, 0, stream>>>(hs, hs_bf);
  tconv_k<<<dim3(128,32), 256, 0, stream>>>(Wq, wq_t, 2048, 8192);
  tconv_k<<<dim3(8,32),   256, 0, stream>>>(Wk, wkv_t, 2048, 512);
  tconv_k<<<dim3(8,32),   256, 0, stream>>>(Wv, wkv_t + (size_t)512*2048, 2048, 512);
  // 1) fused QG+K+V projection: (4096x2048)@(2048x9216), M-major grid
  gemm_k<0><<<dim3(32,72), 256, 0, stream>>>(hs_bf, wq_t, q_bf, gate, 2048, 9216);
  // 1b) Wo transpose (overlays wq_t region — stream-ordered after gemm0)
  tconv_k<<<dim3(32,64), 256, 0, stream>>>(Wo, wo_t, 4096, 2048);
  // 2) RMSNorm + RoPE in place
  normrope_k<<<(2*H_*S_)/4,   256, 0, stream>>>(q_bf, qw, cosp, sinp, H_);
  normrope_k<<<(2*KVH_*S_)/4, 256, 0, stream>>>(k_bf, kw, cosp, sinp, KVH_);
  // 3) causal flash attention + sigmoid-gate (256 balanced blocks)
  flash_k<<<dim3(256), 256, 0, stream>>>(q_bf, k_bf, v_t, gate, attn);
  // 4) output projection: (4096x4096)@(4096x2048), M-major grid
  gemm_k<3><<<dim3(32,16), 256, 0, stream>>>(attn, wo_t, out, nullptr, 4096, 2048);
}

// Round 6
// 604.725 us; speedup vs baseline: 1.1735x; 1.1735x over previous
//
#include <hip/hip_runtime.h>
#include <cstdint>
#include <cstddef>

#define S_   2048
#define H_   16
#define KVH_ 2
#define D_   256

typedef __attribute__((ext_vector_type(4))) float          float4v;
typedef __attribute__((ext_vector_type(4))) float          floatx4;
typedef __attribute__((ext_vector_type(8))) unsigned short ushort8v;
typedef __attribute__((ext_vector_type(4))) unsigned short ushort4v;
typedef __attribute__((ext_vector_type(8))) short          short8;

__device__ __forceinline__ float bf2f(unsigned short u){
  union{float f; unsigned int i;} v; v.i = ((unsigned int)u)<<16; return v.f;
}
__device__ __forceinline__ unsigned short f2bf(float f){
  union{float f; unsigned int i;} v; v.f = f;
  unsigned int r = v.i + 0x7FFFu + ((v.i>>16)&1u);   // RNE
  return (unsigned short)(r>>16);
}
__device__ __forceinline__ void gld16(const void* g, void* l){
  __builtin_amdgcn_global_load_lds(
      (const __attribute__((address_space(1))) unsigned int*)g,
      (__attribute__((address_space(3))) unsigned int*)l, 16, 0, 0);
}

// ---------------------------------------------------------------------------
// Plain fp32 -> bf16 convert (hs). 8 elems/thread.
// ---------------------------------------------------------------------------
__global__ __launch_bounds__(256) void conv_k(
    const float* __restrict__ in, unsigned short* __restrict__ out)
{
  const size_t i = ((size_t)blockIdx.x*256 + threadIdx.x)*8;
  float4v a0 = *(const float4v*)(in + i), a1 = *(const float4v*)(in + i + 4);
  ushort8v u;
#pragma unroll
  for (int e=0;e<4;e++){ u[e]=f2bf(a0[e]); u[e+4]=f2bf(a1[e]); }
  *(ushort8v*)(out + i) = u;
}

// ---------------------------------------------------------------------------
// Transpose-convert: in fp32 [K][N] -> out bf16 [N][K]. 64x64 LDS tiles.
// ---------------------------------------------------------------------------
__global__ __launch_bounds__(256) void tconv_k(
    const float* __restrict__ in, unsigned short* __restrict__ out, int K, int N)
{
  __shared__ unsigned short T[64][72];
  const int n0 = blockIdx.x<<6, k0 = blockIdx.y<<6;
  const int t = threadIdx.x, r = t>>2, c = (t&3)<<4;
  const float* ip = in + (size_t)(k0+r)*N + n0 + c;
  float4v a0=*(const float4v*)ip,     a1=*(const float4v*)(ip+4);
  float4v a2=*(const float4v*)(ip+8), a3=*(const float4v*)(ip+12);
  ushort8v u0,u1;
#pragma unroll
  for (int e=0;e<4;e++){ u0[e]=f2bf(a0[e]); u0[e+4]=f2bf(a1[e]);
                         u1[e]=f2bf(a2[e]); u1[e+4]=f2bf(a3[e]); }
  *(ushort8v*)&T[r][c] = u0; *(ushort8v*)&T[r][c+8] = u1;
  __syncthreads();
  ushort8v o0,o1;
#pragma unroll
  for (int j=0;j<8;j++){ o0[j]=T[c+j][r]; o1[j]=T[c+8+j][r]; }
  unsigned short* op = out + (size_t)(n0+r)*K + k0 + c;
  *(ushort8v*)op = o0; *(ushort8v*)(op+8) = o1;
}

// ---------------------------------------------------------------------------
// GEMM: C(MxN) = A(MxK) @ Bt(NxK)^T, bf16 MFMA, fp32 acc.
// BM=BN=128, BK=32; double-buffered LDS, ONE barrier per k-iter
// (barrier -> prefetch it+1 -> compute it).
// 1D grid, XCD-affine swizzle: bid%8 = XCD slot; each XCD owns a 4-row
// (2 MB) A stripe that stays L2-resident; all XCDs walk B panels in the
// same epoch (L3 broadcast, B fetched from HBM once).
//   gmb = (bid&7)*4 + (bid>>3)&3   (M fixed = 4096 -> 32 m-blocks)
//   gnb = bid>>5
// MODE 0: scatter q(B,H,S,D)/gate(B,S,H,D)/k(B,KVH,S,D)/v^T(B,KVH,S/32,D,32)
// MODE 3: out fp32 row-major [M][N]
// ---------------------------------------------------------------------------
template<int MODE>
__global__ __launch_bounds__(256,2) void gemm_k(
    const unsigned short* __restrict__ A, const unsigned short* __restrict__ Bt,
    void* __restrict__ out0, void* __restrict__ out1, int K, int N)
{
  __shared__ unsigned short Ash[2][128*32];
  __shared__ unsigned short Bsh[2][128*32];
  const int bid  = blockIdx.x;
  const int gm   = ((bid&7)*4 + ((bid>>3)&3))<<7;
  const int gn   = (bid>>5)<<7;
  const int tid  = threadIdx.x;
  const int lane = tid & 63, wave = tid >> 6;
  const int quad = lane >> 4, col = lane & 15;
  const int wm   = (wave>>1)<<6, wn = (wave&1)<<6;
  const int rowoff = lane>>2;
  const int chunk  = (lane&3) ^ (rowoff&3);
  const int ra0 = wave<<4, ra1 = 64 + (wave<<4);
  const unsigned short* Ab = A  + (size_t)gm*K;
  const unsigned short* Bb = Bt + (size_t)gn*K;
  const int cf = (quad ^ (col&3))<<3;

  floatx4 acc[4][4];
#pragma unroll
  for (int i=0;i<4;i++)
#pragma unroll
    for (int j=0;j<4;j++) acc[i][j] = (floatx4)0.f;

  const int niter = K>>5;
  {           // prologue: stage tile 0 into buf 0
    const int ko = chunk*8;
    gld16(Ab + (size_t)(ra0+rowoff)*K + ko, &Ash[0][ra0*32]);
    gld16(Ab + (size_t)(ra1+rowoff)*K + ko, &Ash[0][ra1*32]);
    gld16(Bb + (size_t)(ra0+rowoff)*K + ko, &Bsh[0][ra0*32]);
    gld16(Bb + (size_t)(ra1+rowoff)*K + ko, &Bsh[0][ra1*32]);
  }
  for (int it=0; it<niter; ++it){
    const int buf = it&1;
    __syncthreads();                     // drains tile-it staging
    if (it+1 < niter){                   // prefetch tile it+1 into buf^1
      const int ko = (it+1)*32 + chunk*8;
      gld16(Ab + (size_t)(ra0+rowoff)*K + ko, &Ash[buf^1][ra0*32]);
      gld16(Ab + (size_t)(ra1+rowoff)*K + ko, &Ash[buf^1][ra1*32]);
      gld16(Bb + (size_t)(ra0+rowoff)*K + ko, &Bsh[buf^1][ra0*32]);
      gld16(Bb + (size_t)(ra1+rowoff)*K + ko, &Bsh[buf^1][ra1*32]);
    }
    short8 af[4], bfr[4];
#pragma unroll
    for (int mi=0;mi<4;mi++) af[mi]  = *(const short8*)&Ash[buf][(wm+mi*16+col)*32 + cf];
#pragma unroll
    for (int ni=0;ni<4;ni++) bfr[ni] = *(const short8*)&Bsh[buf][(wn+ni*16+col)*32 + cf];
#pragma unroll
    for (int mi=0;mi<4;mi++)
#pragma unroll
      for (int ni=0;ni<4;ni++)
        acc[mi][ni] = __builtin_amdgcn_mfma_f32_16x16x32_bf16(af[mi], bfr[ni], acc[mi][ni], 0,0,0);
  }

#pragma unroll
  for (int mi=0;mi<4;mi++){
#pragma unroll
    for (int r=0;r<4;r++){
      const int m = gm + wm + mi*16 + quad*4 + r;
      const int b = m >> 11, s = m & 2047;
#pragma unroll
      for (int ni=0;ni<4;ni++){
        const int n = gn + wn + ni*16 + col;
        const float v = acc[mi][ni][r];
        if (MODE==0){
          if (n < 8192){
            const int h = n >> 9, dd = n & 511;
            if (dd < 256)   // q -> (B,H,S,D)
              ((unsigned short*)out0)[(((size_t)b*H_ + h)*S_ + s)*D_ + dd] = f2bf(v);
            else            // gate -> (B,S,H,D)
              ((unsigned short*)out1)[((size_t)m*H_ + h)*D_ + (dd-256)] = f2bf(v);
          } else {
            const int n2 = n - 8192;
            if (n2 < 512){  // k -> (B,KVH,S,D)
              const int kvh = n2 >> 8, dd = n2 & 255;
              ((unsigned short*)out0)[(size_t)(67108864/2) + (((size_t)b*KVH_ + kvh)*S_ + s)*D_ + dd] = f2bf(v);
            } else {        // v^T chunk-tiled (B,KVH,S/32,D,32)
              const int nv2 = n2 - 512;
              const int kvh = nv2 >> 8, dd = nv2 & 255;
              ((unsigned short*)out0)[(size_t)(71303168/2) + ((((size_t)b*KVH_ + kvh)*64 + (s>>5))*256 + dd)*32 + (s&31)] = f2bf(v);
            }
          }
        } else {
          ((float*)out0)[(size_t)m*N + n] = v;
        }
      }
    }
  }
}

// ---------------------------------------------------------------------------
// RMSNorm(D=256) + RoPE(first 64 dims), in-place on bf16 rows. 1 wave / row.
// ---------------------------------------------------------------------------
__global__ __launch_bounds__(256,2) void normrope_k(
    unsigned short* __restrict__ x, const float* __restrict__ w,
    const float* __restrict__ cosp, const float* __restrict__ sinp, int heads)
{
  const int lane = threadIdx.x & 63;
  const int row  = blockIdx.x*4 + (threadIdx.x>>6);
  const int s    = row & (S_-1);
  const int b    = (row / S_) / heads;
  unsigned short* xp = x + (size_t)row * D_;
  const int d = lane*4;
  ushort4v xv = *(const ushort4v*)(xp + d);
  float v0=bf2f(xv[0]), v1=bf2f(xv[1]), v2=bf2f(xv[2]), v3=bf2f(xv[3]);
  float ss = v0*v0+v1*v1+v2*v2+v3*v3;
#pragma unroll
  for (int off=1; off<64; off<<=1) ss += __shfl_xor(ss, off, 64);
  const float rstd = rsqrtf(ss*(1.f/256.f) + 1e-6f);
  float nv[4] = { v0*rstd*(1.f+w[d]),   v1*rstd*(1.f+w[d+1]),
                  v2*rstd*(1.f+w[d+2]), v3*rstd*(1.f+w[d+3]) };
  float ov[4];
#pragma unroll
  for (int j=0;j<4;j++){
    const float other = __shfl_xor(nv[j], 8, 64);
    float o = nv[j];
    if (lane < 16){
      const float c  = cosp[((size_t)b*S_+s)*64 + d + j];
      const float sn = sinp[((size_t)b*S_+s)*64 + d + j];
      o = (lane < 8) ? (nv[j]*c - other*sn) : (nv[j]*c + other*sn);
    }
    ov[j] = o;
  }
  ushort4v ou;
#pragma unroll
  for (int j=0;j<4;j++) ou[j] = f2bf(ov[j]);
  *(ushort4v*)(xp + d) = ou;
}

// ---------------------------------------------------------------------------
// Flash attention, causal, GQA, sigmoid-gate. Balanced AND co-resident:
// 512 blocks = (b, h, pair p in [0,16)); block processes q-strips qt=p and
// qt=31-p (64 q-rows each) -> exactly 68 chunk-iterations per block, and
// 2 blocks/CU co-resident (LDS 70.7 KB) for cross-block latency hiding.
// Per strip: kv chunks of 32, K/V double-buffered LDS via global_load_lds
// prefetch-across-barrier; unpadded XOR-swizzled LDS; no-max softmax
// (|q|=|k|=16 -> exp<=e^16, fp32-safe); coalesced LDS-repacked epilogue.
// ---------------------------------------------------------------------------
__global__ __launch_bounds__(256,2) void flash_k(
    const unsigned short* __restrict__ qb, const unsigned short* __restrict__ kbp,
    const unsigned short* __restrict__ vtp, const unsigned short* __restrict__ gb,
    unsigned short* __restrict__ ob)
{
  // SH (ushorts): K[2][8192] | V[2][8192] | P[4][640]  = 70656 B
  __shared__ unsigned short SH[2*8192 + 2*8192 + 4*640];
  unsigned short* Kb0 = SH;
  unsigned short* Vb0 = SH + 16384;
  const int gid = blockIdx.x;
  const int p   = gid & 15;
  const int h   = (gid>>4) & 15;
  const int b   = gid >> 8;
  const int kvh = h >> 3;
  const int tid = threadIdx.x, wave = tid>>6, lane = tid&63;
  const int quad = lane>>4, col = lane&15;
  unsigned short* Psh = SH + 32768 + wave*640;   // [16][40]

  // per-thread staging offsets (within one 8192-elem chunk)
  int kOff[4], vOff[4];
#pragma unroll
  for (int j=0;j<4;j++){
    const int krow = wave*8 + j*2 + (lane>>5);
    kOff[j] = krow*256 + ((lane&31) ^ (krow&7))*8;
    const int vrow = wave*64 + j*16 + (lane>>2);
    vOff[j] = vrow*32 + ((lane&3) ^ (vrow&3))*8;
  }
  const unsigned short* Kg = kbp + ((size_t)b*KVH_ + kvh)*S_*D_;
  const unsigned short* Vg = vtp + ((size_t)b*KVH_ + kvh)*S_*D_;

  for (int sp=0; sp<2; ++sp){
    const int qt = sp ? (31-p) : p;
    const int q0 = qt*64 + wave*16;
    const int nch = 2*qt + 2;

    // Q fragments (A[m=col][k=quad*8+j])
    short8 qf[8];
    {
      const unsigned short* qr = qb + (((size_t)b*H_ + h)*S_ + (q0+col))*D_;
#pragma unroll
      for (int dc=0; dc<8; ++dc) qf[dc] = *(const short8*)(qr + dc*32 + quad*8);
    }
    floatx4 O[16];
#pragma unroll
    for (int i=0;i<16;i++) O[i] = (floatx4)0.f;
    float lacc[4] = {0.f,0.f,0.f,0.f};

    __syncthreads();   // protect LDS from prior strip's epilogue readers
    // prologue: stage chunk 0 into buf 0
#pragma unroll
    for (int j=0;j<4;j++){
      gld16(Kg + kOff[j], Kb0 + wave*2048 + j*512);
      gld16(Vg + vOff[j], Vb0 + wave*2048 + j*512);
    }

    int buf = 0;
    for (int kc=0; kc<nch; ++kc){
      __syncthreads();                       // drains chunk-kc staging
      if (kc+1 < nch){                       // prefetch kc+1 into buf^1
        const unsigned short* kg = Kg + (size_t)(kc+1)*8192;
        const unsigned short* vg = Vg + (size_t)(kc+1)*8192;
        unsigned short* kl = Kb0 + (buf^1)*8192 + wave*2048;
        unsigned short* vl = Vb0 + (buf^1)*8192 + wave*2048;
#pragma unroll
        for (int j=0;j<4;j++){
          gld16(kg + kOff[j], kl + j*512);
          gld16(vg + vOff[j], vl + j*512);
        }
      }
      const unsigned short* Ksh = Kb0 + buf*8192;
      const unsigned short* Vt  = Vb0 + buf*8192;

      // ---- QK^T (1 m-tile x 2 n-tiles over D=256)
      floatx4 sc[2];
      sc[0]=(floatx4)0.f; sc[1]=(floatx4)0.f;
#pragma unroll
      for (int dc=0; dc<8; ++dc){
#pragma unroll
        for (int nt=0;nt<2;nt++){
          const int row = nt*16+col;
          short8 kf = *(const short8*)&Ksh[row*256 + (((dc*4+quad) ^ (row&7))<<3)];
          sc[nt] = __builtin_amdgcn_mfma_f32_16x16x32_bf16(qf[dc], kf, sc[nt], 0,0,0);
        }
      }
      // ---- mask+exp -> Psh (per-wave, no barrier) -> pf
#pragma unroll
      for (int r=0;r<4;r++){
        const int q = q0 + quad*4 + r;
        float psum = 0.f;
#pragma unroll
        for (int nt=0;nt<2;nt++){
          const int kv = kc*32 + nt*16 + col;
          const float pv = (kv<=q) ? __expf(sc[nt][r]*0.0625f) : 0.f;
          psum += pv;
          Psh[(quad*4+r)*40 + nt*16 + col] = f2bf(pv);
        }
        lacc[r] += psum;
      }
      short8 pf = *(const short8*)&Psh[col*40 + quad*8];
      // ---- PV
#pragma unroll
      for (int nc=0;nc<16;nc++){
        const int row = nc*16+col;
        short8 vf = *(const short8*)&Vt[row*32 + ((quad ^ (row&3))<<3)];
        O[nc] = __builtin_amdgcn_mfma_f32_16x16x32_bf16(pf, vf, O[nc], 0,0,0);
      }
      buf ^= 1;
    }

    // ---- epilogue: repack O via LDS, coalesced gate/store
    __syncthreads();                         // K/V buffers now free
    unsigned short* rep = SH + wave*4096;    // 16q x 256d per wave
#pragma unroll
    for (int r=0;r<4;r++){
      float s = lacc[r];
      s += __shfl_xor(s,1,64); s += __shfl_xor(s,2,64);
      s += __shfl_xor(s,4,64); s += __shfl_xor(s,8,64);
      const float inv = 1.f/s;
      const int rrow = (quad*4 + r)*256;
#pragma unroll
      for (int nc=0;nc<16;nc++)
        rep[rrow + nc*16 + col] = f2bf(O[nc][r]*inv);
    }
    // each j: 64 lanes cover 1KB contiguous (2 q-rows)
#pragma unroll
    for (int j=0;j<8;j++){
      const int e  = j*512 + lane*8;
      const int ql = j*2 + (lane>>5);
      const int d  = (lane&31)*8;
      ushort8v ov = *(const ushort8v*)&rep[e];
      const size_t base = (((size_t)b*S_ + (q0 + ql))*H_ + h)*D_ + d;
      ushort8v gv = *(const ushort8v*)(gb + base);
      ushort8v wv;
#pragma unroll
      for (int k=0;k<8;k++){
        const float gvf = bf2f(gv[k]);
        const float sg  = 1.f/(1.f + __expf(-gvf));
        wv[k] = f2bf(bf2f(ov[k])*sg);
      }
      *(ushort8v*)(ob + base) = wv;
    }
  }
}

// ---------------------------------------------------------------------------
extern "C" void kernel_launch(void* const* d_in, const int* in_sizes, int n_in,
                              void* d_out, int out_size, void* d_ws, size_t ws_size,
                              hipStream_t stream)
{
  const float* hs   = (const float*)d_in[0];
  const float* cosp = (const float*)d_in[1];
  const float* sinp = (const float*)d_in[2];
  const float* Wq   = (const float*)d_in[3];
  const float* Wk   = (const float*)d_in[4];
  const float* Wv   = (const float*)d_in[5];
  const float* Wo   = (const float*)d_in[6];
  const float* qw   = (const float*)d_in[7];
  const float* kw   = (const float*)d_in[8];
  float* out = (float*)d_out;

  char* w = (char*)d_ws;                       // 124 MB total
  unsigned short* q_bf  = (unsigned short*)(w);               // 33.5MB (B,H,S,D)
  unsigned short* gate  = (unsigned short*)(w + 33554432);    // 33.5MB (B,S,H,D)
  unsigned short* k_bf  = (unsigned short*)(w + 67108864);    //  4.2MB (B,KVH,S,D)
  unsigned short* v_t   = (unsigned short*)(w + 71303168);    //  4.2MB (B,KVH,S/32,D,32)
  unsigned short* hs_bf = (unsigned short*)(w + 75497472);    // 16.8MB [4096][2048]
  unsigned short* wq_t  = (unsigned short*)(w + 92274688);    // 33.5MB [8192][2048]
  unsigned short* wkv_t = (unsigned short*)(w + 125829120);   //  4.2MB [1024][2048]
  unsigned short* wo_t  = (unsigned short*)(w + 92274688);    // 16.8MB overlay after gemm0
  unsigned short* attn  = gate;                               // in-place overlay

  // 0) convert/transpose operands to bf16
  conv_k<<<4096, 256, 0, stream>>>(hs, hs_bf);
  tconv_k<<<dim3(128,32), 256, 0, stream>>>(Wq, wq_t, 2048, 8192);
  tconv_k<<<dim3(8,32),   256, 0, stream>>>(Wk, wkv_t, 2048, 512);
  tconv_k<<<dim3(8,32),   256, 0, stream>>>(Wv, wkv_t + (size_t)512*2048, 2048, 512);
  // 1) fused QG+K+V projection: (4096x2048)@(2048x9216), XCD-swizzled 1D grid
  gemm_k<0><<<dim3(2304), 256, 0, stream>>>(hs_bf, wq_t, q_bf, gate, 2048, 9216);
  // 1b) Wo transpose (overlays wq_t region — stream-ordered after gemm0)
  tconv_k<<<dim3(32,64), 256, 0, stream>>>(Wo, wo_t, 4096, 2048);
  // 2) RMSNorm + RoPE in place
  normrope_k<<<(2*H_*S_)/4,   256, 0, stream>>>(q_bf, qw, cosp, sinp, H_);
  normrope_k<<<(2*KVH_*S_)/4, 256, 0, stream>>>(k_bf, kw, cosp, sinp, KVH_);
  // 3) causal flash attention + sigmoid-gate (512 balanced co-resident blocks)
  flash_k<<<dim3(512), 256, 0, stream>>>(q_bf, k_bf, v_t, gate, attn);
  // 4) output projection: (4096x4096)@(4096x2048), XCD-swizzled 1D grid
  gemm_k<3><<<dim3(512), 256, 0, stream>>>(attn, wo_t, out, nullptr, 4096, 2048);
}